// Round 1
// baseline (1479.461 us; speedup 1.0000x reference)
//
#include <hip/hip_runtime.h>
#include <math.h>

#define NN 100000
#define FIN 256
#define D1 64
#define C2 47

__global__ __launch_bounds__(256) void k_init_deg(float* __restrict__ deg) {
    int i = blockIdx.x * 256 + threadIdx.x;
    if (i < NN) deg[i] = 1.0f;  // self-loop contribution
}

__global__ __launch_bounds__(256) void k_count_deg(const int* __restrict__ dst, int E,
                                                   float* __restrict__ deg) {
    int e = blockIdx.x * 256 + threadIdx.x;
    if (e < E) unsafeAtomicAdd(&deg[dst[e]], 1.0f);
}

__global__ __launch_bounds__(256) void k_dinv(float* __restrict__ deg) {
    int i = blockIdx.x * 256 + threadIdx.x;
    if (i < NN) {
        float d = deg[i];
        deg[i] = (d > 0.f) ? rsqrtf(d) : 0.f;
    }
}

// C[M,N] = A[M,K] @ B[K,N], fp32. BM=BN=64, BK=16, 256 threads, 4x4 micro-tiles.
__global__ __launch_bounds__(256) void k_gemm(const float* __restrict__ A,
                                              const float* __restrict__ B,
                                              float* __restrict__ C,
                                              int M, int N, int K) {
    __shared__ float As[64][17];   // [m][k], +1 pad
    __shared__ float Bs[16][64];   // [k][n]

    const int tid = threadIdx.x;
    const int tx = tid & 15, ty = tid >> 4;
    const int bm = blockIdx.x * 64;
    const int bn = blockIdx.y * 64;
    const int row0 = bm + ty * 4, col0 = bn + tx * 4;

    float acc[4][4] = {};

    const int am  = tid >> 2;         // 0..63 : A tile row
    const int ak  = (tid & 3) * 4;    // 0,4,8,12 : A tile k quad
    const int bns = tid & 63;         // 0..63 : B tile col
    const int bk0 = (tid >> 6) * 4;   // 0,4,8,12 : B tile k quad

    for (int kt = 0; kt < K; kt += 16) {
        float4 av = make_float4(0.f, 0.f, 0.f, 0.f);
        int arow = bm + am;
        if (arow < M)
            av = *reinterpret_cast<const float4*>(A + (size_t)arow * K + kt + ak);
        As[am][ak + 0] = av.x; As[am][ak + 1] = av.y;
        As[am][ak + 2] = av.z; As[am][ak + 3] = av.w;

        #pragma unroll
        for (int j = 0; j < 4; ++j) {
            int k = bk0 + j;
            int col = bn + bns;
            Bs[k][bns] = (col < N) ? B[(size_t)(kt + k) * N + col] : 0.f;
        }
        __syncthreads();

        #pragma unroll
        for (int k = 0; k < 16; ++k) {
            float4 bv = *reinterpret_cast<const float4*>(&Bs[k][tx * 4]);
            float a0 = As[ty * 4 + 0][k];
            float a1 = As[ty * 4 + 1][k];
            float a2 = As[ty * 4 + 2][k];
            float a3 = As[ty * 4 + 3][k];
            acc[0][0] += a0 * bv.x; acc[0][1] += a0 * bv.y; acc[0][2] += a0 * bv.z; acc[0][3] += a0 * bv.w;
            acc[1][0] += a1 * bv.x; acc[1][1] += a1 * bv.y; acc[1][2] += a1 * bv.z; acc[1][3] += a1 * bv.w;
            acc[2][0] += a2 * bv.x; acc[2][1] += a2 * bv.y; acc[2][2] += a2 * bv.z; acc[2][3] += a2 * bv.w;
            acc[3][0] += a3 * bv.x; acc[3][1] += a3 * bv.y; acc[3][2] += a3 * bv.z; acc[3][3] += a3 * bv.w;
        }
        __syncthreads();
    }

    #pragma unroll
    for (int i = 0; i < 4; ++i) {
        int r = row0 + i;
        if (r < M) {
            #pragma unroll
            for (int j = 0; j < 4; ++j) {
                int c = col0 + j;
                if (c < N) C[(size_t)r * N + c] = acc[i][j];
            }
        }
    }
}

// Edge scatter, D=64 dims: 16 threads/edge, float4 gather + 4 atomics each.
__global__ __launch_bounds__(256) void k_agg64(const int* __restrict__ src,
                                               const int* __restrict__ dst,
                                               const float* __restrict__ dinv,
                                               const float* __restrict__ h,
                                               float* __restrict__ out, int E) {
    int t = blockIdx.x * 256 + threadIdx.x;
    int e = t >> 4;
    if (e >= E) return;
    int q = (t & 15) * 4;
    int s = src[e], d = dst[e];
    float nrm = dinv[s] * dinv[d];
    const float4 hv = *reinterpret_cast<const float4*>(h + (size_t)s * 64 + q);
    float* o = out + (size_t)d * 64 + q;
    unsafeAtomicAdd(o + 0, nrm * hv.x);
    unsafeAtomicAdd(o + 1, nrm * hv.y);
    unsafeAtomicAdd(o + 2, nrm * hv.z);
    unsafeAtomicAdd(o + 3, nrm * hv.w);
}

// agg += dinv[i]^2 * h[i]  (self-loop) + b1, then ReLU.  NN*64 elements.
__global__ __launch_bounds__(256) void k_relu_bias_self(float* __restrict__ agg,
                                                        const float* __restrict__ h,
                                                        const float* __restrict__ dinv,
                                                        const float* __restrict__ b1) {
    int idx = blockIdx.x * 256 + threadIdx.x;
    if (idx < NN * D1) {
        int node = idx >> 6, dd = idx & 63;
        float di = dinv[node];
        float v = agg[idx] + di * di * h[idx] + b1[dd];
        agg[idx] = fmaxf(v, 0.f);
    }
}

// Edge scatter, C=47 dims: 64 threads/edge (47 active).
__global__ __launch_bounds__(256) void k_agg47(const int* __restrict__ src,
                                               const int* __restrict__ dst,
                                               const float* __restrict__ dinv,
                                               const float* __restrict__ h,
                                               float* __restrict__ out, int E) {
    int t = blockIdx.x * 256 + threadIdx.x;
    int e = t >> 6, dd = t & 63;
    if (e >= E || dd >= C2) return;
    int s = src[e], d = dst[e];
    float nrm = dinv[s] * dinv[d];
    unsafeAtomicAdd(out + (size_t)d * C2 + dd, nrm * h[(size_t)s * C2 + dd]);
}

// Per row (one wave each): v = out + dinv^2*h2 + b2, then log_softmax, in place.
__global__ __launch_bounds__(256) void k_final(float* __restrict__ out,
                                               const float* __restrict__ h2,
                                               const float* __restrict__ dinv,
                                               const float* __restrict__ b2) {
    int t = blockIdx.x * 256 + threadIdx.x;
    int row = t >> 6, lane = t & 63;
    if (row >= NN) return;
    float val = 0.f, v = -INFINITY;
    if (lane < C2) {
        float di = dinv[row];
        val = out[(size_t)row * C2 + lane] + di * di * h2[(size_t)row * C2 + lane] + b2[lane];
        v = val;
    }
    #pragma unroll
    for (int off = 32; off; off >>= 1) v = fmaxf(v, __shfl_xor(v, off));
    float ex = (lane < C2) ? expf(val - v) : 0.f;
    #pragma unroll
    for (int off = 32; off; off >>= 1) ex += __shfl_xor(ex, off);
    if (lane < C2) out[(size_t)row * C2 + lane] = val - v - logf(ex);
}

extern "C" void kernel_launch(void* const* d_in, const int* in_sizes, int n_in,
                              void* d_out, int out_size, void* d_ws, size_t ws_size,
                              hipStream_t stream) {
    const float* x  = (const float*)d_in[0];
    const int*   ei = (const int*)d_in[1];
    const float* W1 = (const float*)d_in[2];
    const float* b1 = (const float*)d_in[3];
    const float* W2 = (const float*)d_in[4];
    const float* b2 = (const float*)d_in[5];
    float* out = (float*)d_out;

    const int E = in_sizes[1] / 2;
    const int* src = ei;
    const int* dst = ei + E;

    char* ws = (char*)d_ws;
    float* dinv = (float*)ws;                                  // NN floats
    float* bufA = (float*)(ws + (512 << 10));                  // NN*64 (h1, later h2)
    float* bufB = (float*)(ws + (512 << 10) + (size_t)NN * D1 * 4); // NN*64 (agg1)

    hipMemsetAsync(bufB, 0, (size_t)NN * D1 * 4, stream);
    hipMemsetAsync(out, 0, (size_t)NN * C2 * 4, stream);

    k_init_deg<<<(NN + 255) / 256, 256, 0, stream>>>(dinv);
    k_count_deg<<<(E + 255) / 256, 256, 0, stream>>>(dst, E, dinv);
    k_dinv<<<(NN + 255) / 256, 256, 0, stream>>>(dinv);

    dim3 g1((NN + 63) / 64, 1);
    k_gemm<<<g1, 256, 0, stream>>>(x, W1, bufA, NN, D1, FIN);

    k_agg64<<<(E * 16 + 255) / 256, 256, 0, stream>>>(src, dst, dinv, bufA, bufB, E);
    k_relu_bias_self<<<(NN * D1 + 255) / 256, 256, 0, stream>>>(bufB, bufA, dinv, b1);

    k_gemm<<<g1, 256, 0, stream>>>(bufB, W2, bufA, NN, C2, D1);

    k_agg47<<<(E * 64 + 255) / 256, 256, 0, stream>>>(src, dst, dinv, bufA, out, E);
    k_final<<<(NN * 64 + 255) / 256, 256, 0, stream>>>(out, bufA, dinv, b2);
}

// Round 2
// 477.825 us; speedup vs baseline: 3.0962x; 3.0962x over previous
//
#include <hip/hip_runtime.h>
#include <math.h>

#define NN 100000
#define FIN 256
#define D1 64
#define C2 47

// ---------------- degree / norm ----------------
__global__ __launch_bounds__(256) void k_count(const int* __restrict__ dst, int E,
                                               int* __restrict__ cnt) {
    int e = blockIdx.x * 256 + threadIdx.x;
    if (e < E) atomicAdd(&cnt[dst[e]], 1);
}

__global__ __launch_bounds__(256) void k_dinv(const int* __restrict__ cnt,
                                              float* __restrict__ dinv) {
    int i = blockIdx.x * 256 + threadIdx.x;
    if (i < NN) dinv[i] = rsqrtf((float)cnt[i] + 1.0f);  // +1 = self-loop
}

// ---------------- exclusive scan (3-phase, 1024 elems/block) ----------------
__global__ __launch_bounds__(256) void k_scanA(const int* __restrict__ cnt,
                                               int* __restrict__ part, int n) {
    __shared__ int sd[256];
    int t = threadIdx.x, base = blockIdx.x * 1024;
    int s = 0;
    #pragma unroll
    for (int j = 0; j < 4; ++j) {
        int idx = base + j * 256 + t;
        if (idx < n) s += cnt[idx];
    }
    sd[t] = s; __syncthreads();
    for (int off = 128; off; off >>= 1) {
        if (t < off) sd[t] += sd[t + off];
        __syncthreads();
    }
    if (!t) part[blockIdx.x] = sd[0];
}

__global__ __launch_bounds__(256) void k_scanB(int* __restrict__ part, int nb) {
    __shared__ int sd[256];
    int t = threadIdx.x;
    int v = (t < nb) ? part[t] : 0;
    sd[t] = v; __syncthreads();
    for (int off = 1; off < 256; off <<= 1) {
        int u = (t >= off) ? sd[t - off] : 0;
        __syncthreads();
        sd[t] += u;
        __syncthreads();
    }
    if (t < nb) part[t] = sd[t] - v;  // exclusive
}

__global__ __launch_bounds__(256) void k_scanC(const int* __restrict__ cnt,
                                               const int* __restrict__ part,
                                               int* __restrict__ rowptr, int n) {
    __shared__ int sd[256];
    int t = threadIdx.x, base = blockIdx.x * 1024;
    int i0 = base + t * 4;
    int a0 = 0, a1 = 0, a2 = 0, a3 = 0;
    if (i0 + 0 < n) a0 = cnt[i0 + 0];
    if (i0 + 1 < n) a1 = cnt[i0 + 1];
    if (i0 + 2 < n) a2 = cnt[i0 + 2];
    if (i0 + 3 < n) a3 = cnt[i0 + 3];
    int ts = a0 + a1 + a2 + a3;
    sd[t] = ts; __syncthreads();
    for (int off = 1; off < 256; off <<= 1) {
        int u = (t >= off) ? sd[t - off] : 0;
        __syncthreads();
        sd[t] += u;
        __syncthreads();
    }
    int run = part[blockIdx.x] + sd[t] - ts;  // exclusive offset for this thread
    if (i0 + 0 < n) { rowptr[i0 + 0] = run; run += a0; }
    if (i0 + 1 < n) { rowptr[i0 + 1] = run; run += a1; }
    if (i0 + 2 < n) { rowptr[i0 + 2] = run; run += a2; }
    if (i0 + 3 < n) { rowptr[i0 + 3] = run; run += a3; }
}

__global__ void k_setE(int* __restrict__ rowptr, int E) { rowptr[NN] = E; }

__global__ __launch_bounds__(256) void k_fill(const int* __restrict__ src,
                                              const int* __restrict__ dst, int E,
                                              const int* __restrict__ rowptr,
                                              int* __restrict__ cur,
                                              int* __restrict__ colidx) {
    int e = blockIdx.x * 256 + threadIdx.x;
    if (e < E) {
        int d = dst[e];
        int p = rowptr[d] + atomicAdd(&cur[d], 1);
        colidx[p] = src[e];
    }
}

// ---------------- GEMM: C[M,N] = A[M,K] @ B[K,N], fp32 ----------------
__global__ __launch_bounds__(256) void k_gemm(const float* __restrict__ A,
                                              const float* __restrict__ B,
                                              float* __restrict__ C,
                                              int M, int N, int K) {
    __shared__ float As[64][17];
    __shared__ float Bs[16][64];

    const int tid = threadIdx.x;
    const int tx = tid & 15, ty = tid >> 4;
    const int bm = blockIdx.x * 64;
    const int bn = blockIdx.y * 64;
    const int row0 = bm + ty * 4, col0 = bn + tx * 4;

    float acc[4][4] = {};

    const int am  = tid >> 2;
    const int ak  = (tid & 3) * 4;
    const int bns = tid & 63;
    const int bk0 = (tid >> 6) * 4;

    for (int kt = 0; kt < K; kt += 16) {
        float4 av = make_float4(0.f, 0.f, 0.f, 0.f);
        int arow = bm + am;
        if (arow < M)
            av = *reinterpret_cast<const float4*>(A + (size_t)arow * K + kt + ak);
        As[am][ak + 0] = av.x; As[am][ak + 1] = av.y;
        As[am][ak + 2] = av.z; As[am][ak + 3] = av.w;

        #pragma unroll
        for (int j = 0; j < 4; ++j) {
            int k = bk0 + j;
            int col = bn + bns;
            Bs[k][bns] = (col < N) ? B[(size_t)(kt + k) * N + col] : 0.f;
        }
        __syncthreads();

        #pragma unroll
        for (int k = 0; k < 16; ++k) {
            float4 bv = *reinterpret_cast<const float4*>(&Bs[k][tx * 4]);
            float a0 = As[ty * 4 + 0][k];
            float a1 = As[ty * 4 + 1][k];
            float a2 = As[ty * 4 + 2][k];
            float a3 = As[ty * 4 + 3][k];
            acc[0][0] += a0 * bv.x; acc[0][1] += a0 * bv.y; acc[0][2] += a0 * bv.z; acc[0][3] += a0 * bv.w;
            acc[1][0] += a1 * bv.x; acc[1][1] += a1 * bv.y; acc[1][2] += a1 * bv.z; acc[1][3] += a1 * bv.w;
            acc[2][0] += a2 * bv.x; acc[2][1] += a2 * bv.y; acc[2][2] += a2 * bv.z; acc[2][3] += a2 * bv.w;
            acc[3][0] += a3 * bv.x; acc[3][1] += a3 * bv.y; acc[3][2] += a3 * bv.z; acc[3][3] += a3 * bv.w;
        }
        __syncthreads();
    }

    #pragma unroll
    for (int i = 0; i < 4; ++i) {
        int r = row0 + i;
        if (r < M) {
            #pragma unroll
            for (int j = 0; j < 4; ++j) {
                int c = col0 + j;
                if (c < N) C[(size_t)r * N + c] = acc[i][j];
            }
        }
    }
}

// ---------------- gather layer 1: agg + self + bias + ReLU, D=64 ----------------
// one wave per node, lane = feature dim
__global__ __launch_bounds__(256) void k_gather64(const int* __restrict__ rowptr,
                                                  const int* __restrict__ colidx,
                                                  const float* __restrict__ dinv,
                                                  const float* __restrict__ h,
                                                  const float* __restrict__ b1,
                                                  float* __restrict__ out) {
    int node = blockIdx.x * 4 + (threadIdx.x >> 6);
    int lane = threadIdx.x & 63;
    if (node >= NN) return;
    int beg = rowptr[node], end = rowptr[node + 1];
    float acc = 0.f;
    for (int e = beg; e < end; ++e) {
        int s = colidx[e];                    // wave-uniform
        acc += dinv[s] * h[(size_t)s * D1 + lane];
    }
    float dd = dinv[node];
    acc = dd * acc + dd * dd * h[(size_t)node * D1 + lane] + b1[lane];
    out[(size_t)node * D1 + lane] = fmaxf(acc, 0.f);
}

// ---------------- gather layer 2 + log_softmax, C=47 ----------------
__global__ __launch_bounds__(256) void k_gather47_sm(const int* __restrict__ rowptr,
                                                     const int* __restrict__ colidx,
                                                     const float* __restrict__ dinv,
                                                     const float* __restrict__ h,
                                                     const float* __restrict__ b2,
                                                     float* __restrict__ out) {
    int node = blockIdx.x * 4 + (threadIdx.x >> 6);
    int lane = threadIdx.x & 63;
    if (node >= NN) return;
    int beg = rowptr[node], end = rowptr[node + 1];
    float acc = 0.f;
    bool act = lane < C2;
    for (int e = beg; e < end; ++e) {
        int s = colidx[e];                    // wave-uniform
        float ds = dinv[s];
        if (act) acc += ds * h[(size_t)s * C2 + lane];
    }
    float dd = dinv[node];
    float val = 0.f;
    if (act) val = dd * acc + dd * dd * h[(size_t)node * C2 + lane] + b2[lane];

    float m = act ? val : -INFINITY;
    #pragma unroll
    for (int off = 32; off; off >>= 1) m = fmaxf(m, __shfl_xor(m, off));
    float ex = act ? expf(val - m) : 0.f;
    #pragma unroll
    for (int off = 32; off; off >>= 1) ex += __shfl_xor(ex, off);
    if (act) out[(size_t)node * C2 + lane] = val - m - logf(ex);
}

extern "C" void kernel_launch(void* const* d_in, const int* in_sizes, int n_in,
                              void* d_out, int out_size, void* d_ws, size_t ws_size,
                              hipStream_t stream) {
    const float* x  = (const float*)d_in[0];
    const int*   ei = (const int*)d_in[1];
    const float* W1 = (const float*)d_in[2];
    const float* b1 = (const float*)d_in[3];
    const float* W2 = (const float*)d_in[4];
    const float* b2 = (const float*)d_in[5];
    float* out = (float*)d_out;

    const int E = in_sizes[1] / 2;
    const int* src = ei;
    const int* dst = ei + E;

    char* ws = (char*)d_ws;
    float* dinv    = (float*)(ws);                    // 512 KB slot
    int*   cnt     = (int*)(ws + (512 << 10));        // 512 KB slot (counts, then cursor)
    int*   rowptr  = (int*)(ws + (1024 << 10));       // 512 KB slot (NN+1 ints)
    int*   part    = (int*)(ws + (1536 << 10));       // 4 KB
    int*   colidx  = (int*)(ws + (2048 << 10));       // 5 MB slot (E ints)
    float* bufA    = (float*)(ws + (8192 << 10));     // 25.6 MB (h1 / h2)
    float* bufB    = (float*)(ws + (size_t)(8192 << 10) + (size_t)NN * D1 * 4); // 25.6 MB

    const int nb = (NN + 1023) / 1024;  // scan blocks

    hipMemsetAsync(cnt, 0, NN * sizeof(int), stream);
    k_count<<<(E + 255) / 256, 256, 0, stream>>>(dst, E, cnt);
    k_dinv<<<(NN + 255) / 256, 256, 0, stream>>>(cnt, dinv);

    k_scanA<<<nb, 256, 0, stream>>>(cnt, part, NN);
    k_scanB<<<1, 256, 0, stream>>>(part, nb);
    k_scanC<<<nb, 256, 0, stream>>>(cnt, part, rowptr, NN);
    k_setE<<<1, 1, 0, stream>>>(rowptr, E);

    hipMemsetAsync(cnt, 0, NN * sizeof(int), stream);  // reuse as cursor
    k_fill<<<(E + 255) / 256, 256, 0, stream>>>(src, dst, E, rowptr, cnt, colidx);

    dim3 g1((NN + 63) / 64, 1);
    k_gemm<<<g1, 256, 0, stream>>>(x, W1, bufA, NN, D1, FIN);
    k_gather64<<<(NN + 3) / 4, 256, 0, stream>>>(rowptr, colidx, dinv, bufA, b1, bufB);

    k_gemm<<<g1, 256, 0, stream>>>(bufB, W2, bufA, NN, C2, D1);
    k_gather47_sm<<<(NN + 3) / 4, 256, 0, stream>>>(rowptr, colidx, dinv, bufA, b2, out);
}

// Round 3
// 351.917 us; speedup vs baseline: 4.2040x; 1.3578x over previous
//
#include <hip/hip_runtime.h>
#include <math.h>

#define NN 100000
#define FIN 256
#define D1 64
#define C2 47

// ---------------- degree / norm ----------------
__global__ __launch_bounds__(256) void k_count(const int* __restrict__ dst, int E,
                                               int* __restrict__ cnt) {
    int e = blockIdx.x * 256 + threadIdx.x;
    if (e < E) atomicAdd(&cnt[dst[e]], 1);
}

__global__ __launch_bounds__(256) void k_dinv(const int* __restrict__ cnt,
                                              float* __restrict__ dinv) {
    int i = blockIdx.x * 256 + threadIdx.x;
    if (i < NN) dinv[i] = rsqrtf((float)cnt[i] + 1.0f);  // +1 = self-loop
}

// ---------------- exclusive scan (3-phase, 1024 elems/block) ----------------
__global__ __launch_bounds__(256) void k_scanA(const int* __restrict__ cnt,
                                               int* __restrict__ part, int n) {
    __shared__ int sd[256];
    int t = threadIdx.x, base = blockIdx.x * 1024;
    int s = 0;
    #pragma unroll
    for (int j = 0; j < 4; ++j) {
        int idx = base + j * 256 + t;
        if (idx < n) s += cnt[idx];
    }
    sd[t] = s; __syncthreads();
    for (int off = 128; off; off >>= 1) {
        if (t < off) sd[t] += sd[t + off];
        __syncthreads();
    }
    if (!t) part[blockIdx.x] = sd[0];
}

__global__ __launch_bounds__(256) void k_scanB(int* __restrict__ part, int nb) {
    __shared__ int sd[256];
    int t = threadIdx.x;
    int v = (t < nb) ? part[t] : 0;
    sd[t] = v; __syncthreads();
    for (int off = 1; off < 256; off <<= 1) {
        int u = (t >= off) ? sd[t - off] : 0;
        __syncthreads();
        sd[t] += u;
        __syncthreads();
    }
    if (t < nb) part[t] = sd[t] - v;  // exclusive
}

__global__ __launch_bounds__(256) void k_scanC(const int* __restrict__ cnt,
                                               const int* __restrict__ part,
                                               int* __restrict__ rowptr, int n) {
    __shared__ int sd[256];
    int t = threadIdx.x, base = blockIdx.x * 1024;
    int i0 = base + t * 4;
    int a0 = 0, a1 = 0, a2 = 0, a3 = 0;
    if (i0 + 0 < n) a0 = cnt[i0 + 0];
    if (i0 + 1 < n) a1 = cnt[i0 + 1];
    if (i0 + 2 < n) a2 = cnt[i0 + 2];
    if (i0 + 3 < n) a3 = cnt[i0 + 3];
    int ts = a0 + a1 + a2 + a3;
    sd[t] = ts; __syncthreads();
    for (int off = 1; off < 256; off <<= 1) {
        int u = (t >= off) ? sd[t - off] : 0;
        __syncthreads();
        sd[t] += u;
        __syncthreads();
    }
    int run = part[blockIdx.x] + sd[t] - ts;  // exclusive offset for this thread
    if (i0 + 0 < n) { rowptr[i0 + 0] = run; run += a0; }
    if (i0 + 1 < n) { rowptr[i0 + 1] = run; run += a1; }
    if (i0 + 2 < n) { rowptr[i0 + 2] = run; run += a2; }
    if (i0 + 3 < n) { rowptr[i0 + 3] = run; run += a3; }
}

__global__ void k_setE(int* __restrict__ rowptr, int E) { rowptr[NN] = E; }

__global__ __launch_bounds__(256) void k_fill(const int* __restrict__ src,
                                              const int* __restrict__ dst, int E,
                                              const int* __restrict__ rowptr,
                                              int* __restrict__ cur,
                                              int* __restrict__ colidx) {
    int e = blockIdx.x * 256 + threadIdx.x;
    if (e < E) {
        int d = dst[e];
        int p = rowptr[d] + atomicAdd(&cur[d], 1);
        colidx[p] = src[e];
    }
}

// ---------------- GEMM: C[M,N] = rowscale[r] * (A[M,K] @ B[K,N]), fp32 --------
__global__ __launch_bounds__(256) void k_gemm(const float* __restrict__ A,
                                              const float* __restrict__ B,
                                              const float* __restrict__ rowscale,
                                              float* __restrict__ C,
                                              int M, int N, int K) {
    __shared__ float As[16][68];   // [k][m], padded so float4 reads stay 16B-aligned
    __shared__ float Bs[16][64];   // [k][n]

    const int tid = threadIdx.x;
    const int tx = tid & 15, ty = tid >> 4;
    const int bm = blockIdx.x * 64;
    const int bn = blockIdx.y * 64;
    const int row0 = bm + ty * 4, col0 = bn + tx * 4;

    float acc[4][4] = {};

    const int am  = tid >> 2;         // 0..63 : A tile row
    const int ak  = (tid & 3) * 4;    // 0,4,8,12 : A tile k quad
    const int bns = tid & 63;         // 0..63 : B tile col
    const int bk0 = (tid >> 6) * 4;   // 0,4,8,12 : B tile k quad

    for (int kt = 0; kt < K; kt += 16) {
        float4 av = make_float4(0.f, 0.f, 0.f, 0.f);
        int arow = bm + am;
        if (arow < M)
            av = *reinterpret_cast<const float4*>(A + (size_t)arow * K + kt + ak);
        As[ak + 0][am] = av.x; As[ak + 1][am] = av.y;
        As[ak + 2][am] = av.z; As[ak + 3][am] = av.w;

        #pragma unroll
        for (int j = 0; j < 4; ++j) {
            int k = bk0 + j;
            int col = bn + bns;
            Bs[k][bns] = (col < N) ? B[(size_t)(kt + k) * N + col] : 0.f;
        }
        __syncthreads();

        #pragma unroll
        for (int k = 0; k < 16; ++k) {
            float4 av2 = *reinterpret_cast<const float4*>(&As[k][ty * 4]);
            float4 bv  = *reinterpret_cast<const float4*>(&Bs[k][tx * 4]);
            acc[0][0] += av2.x * bv.x; acc[0][1] += av2.x * bv.y; acc[0][2] += av2.x * bv.z; acc[0][3] += av2.x * bv.w;
            acc[1][0] += av2.y * bv.x; acc[1][1] += av2.y * bv.y; acc[1][2] += av2.y * bv.z; acc[1][3] += av2.y * bv.w;
            acc[2][0] += av2.z * bv.x; acc[2][1] += av2.z * bv.y; acc[2][2] += av2.z * bv.z; acc[2][3] += av2.z * bv.w;
            acc[3][0] += av2.w * bv.x; acc[3][1] += av2.w * bv.y; acc[3][2] += av2.w * bv.z; acc[3][3] += av2.w * bv.w;
        }
        __syncthreads();
    }

    #pragma unroll
    for (int i = 0; i < 4; ++i) {
        int r = row0 + i;
        if (r < M) {
            float sc = rowscale[r];
            #pragma unroll
            for (int j = 0; j < 4; ++j) {
                int c = col0 + j;
                if (c < N) C[(size_t)r * N + c] = sc * acc[i][j];
            }
        }
    }
}

// ---------------- gather layer 1: Σ hs[s] + self + bias + ReLU, D=64 ----------
// one wave per node, lane = feature dim; hs rows are pre-scaled by dinv[src].
__global__ __launch_bounds__(256) void k_gather64(const int* __restrict__ rowptr,
                                                  const int* __restrict__ colidx,
                                                  const float* __restrict__ dinv,
                                                  const float* __restrict__ hs,
                                                  const float* __restrict__ b1,
                                                  float* __restrict__ out) {
    int node = blockIdx.x * 4 + (threadIdx.x >> 6);
    int lane = threadIdx.x & 63;
    if (node >= NN) return;
    int beg = rowptr[node], end = rowptr[node + 1];
    float a0 = hs[(size_t)node * D1 + lane];  // self-loop term
    float a1 = 0.f, a2 = 0.f, a3 = 0.f;
    int e = beg;
    for (; e + 4 <= end; e += 4) {
        int s0 = colidx[e + 0], s1 = colidx[e + 1];
        int s2 = colidx[e + 2], s3 = colidx[e + 3];
        a0 += hs[(size_t)s0 * D1 + lane];
        a1 += hs[(size_t)s1 * D1 + lane];
        a2 += hs[(size_t)s2 * D1 + lane];
        a3 += hs[(size_t)s3 * D1 + lane];
    }
    for (; e < end; ++e) a0 += hs[(size_t)colidx[e] * D1 + lane];
    float acc = (a0 + a1) + (a2 + a3);
    float dd = dinv[node];
    out[(size_t)node * D1 + lane] = fmaxf(fmaf(dd, acc, b1[lane]), 0.f);
}

// ---------------- gather layer 2 + log_softmax, C=47 ----------------
__global__ __launch_bounds__(256) void k_gather47_sm(const int* __restrict__ rowptr,
                                                     const int* __restrict__ colidx,
                                                     const float* __restrict__ dinv,
                                                     const float* __restrict__ hs,
                                                     const float* __restrict__ b2,
                                                     float* __restrict__ out) {
    int node = blockIdx.x * 4 + (threadIdx.x >> 6);
    int lane = threadIdx.x & 63;
    if (node >= NN) return;
    int beg = rowptr[node], end = rowptr[node + 1];
    bool act = lane < C2;
    int ll = act ? lane : 0;
    float a0 = hs[(size_t)node * C2 + ll];  // self-loop term
    float a1 = 0.f, a2 = 0.f, a3 = 0.f;
    int e = beg;
    for (; e + 4 <= end; e += 4) {
        int s0 = colidx[e + 0], s1 = colidx[e + 1];
        int s2 = colidx[e + 2], s3 = colidx[e + 3];
        a0 += hs[(size_t)s0 * C2 + ll];
        a1 += hs[(size_t)s1 * C2 + ll];
        a2 += hs[(size_t)s2 * C2 + ll];
        a3 += hs[(size_t)s3 * C2 + ll];
    }
    for (; e < end; ++e) a0 += hs[(size_t)colidx[e] * C2 + ll];
    float acc = (a0 + a1) + (a2 + a3);
    float dd = dinv[node];
    float val = fmaf(dd, acc, b2[ll]);

    float m = act ? val : -INFINITY;
    #pragma unroll
    for (int off = 32; off; off >>= 1) m = fmaxf(m, __shfl_xor(m, off));
    float ex = act ? expf(val - m) : 0.f;
    #pragma unroll
    for (int off = 32; off; off >>= 1) ex += __shfl_xor(ex, off);
    if (act) out[(size_t)node * C2 + lane] = val - m - logf(ex);
}

extern "C" void kernel_launch(void* const* d_in, const int* in_sizes, int n_in,
                              void* d_out, int out_size, void* d_ws, size_t ws_size,
                              hipStream_t stream) {
    const float* x  = (const float*)d_in[0];
    const int*   ei = (const int*)d_in[1];
    const float* W1 = (const float*)d_in[2];
    const float* b1 = (const float*)d_in[3];
    const float* W2 = (const float*)d_in[4];
    const float* b2 = (const float*)d_in[5];
    float* out = (float*)d_out;

    const int E = in_sizes[1] / 2;
    const int* src = ei;
    const int* dst = ei + E;

    char* ws = (char*)d_ws;
    float* dinv    = (float*)(ws);                    // 512 KB slot
    int*   cnt     = (int*)(ws + (512 << 10));        // 512 KB slot (counts, then cursor)
    int*   rowptr  = (int*)(ws + (1024 << 10));       // 512 KB slot (NN+1 ints)
    int*   part    = (int*)(ws + (1536 << 10));       // 4 KB
    int*   colidx  = (int*)(ws + (2048 << 10));       // 5 MB slot (E ints)
    float* bufA    = (float*)(ws + (8192 << 10));     // 25.6 MB (hs1 / hs2)
    float* bufB    = (float*)(ws + (size_t)(8192 << 10) + (size_t)NN * D1 * 4); // 25.6 MB

    const int nb = (NN + 1023) / 1024;  // scan blocks

    hipMemsetAsync(cnt, 0, NN * sizeof(int), stream);
    k_count<<<(E + 255) / 256, 256, 0, stream>>>(dst, E, cnt);
    k_dinv<<<(NN + 255) / 256, 256, 0, stream>>>(cnt, dinv);

    k_scanA<<<nb, 256, 0, stream>>>(cnt, part, NN);
    k_scanB<<<1, 256, 0, stream>>>(part, nb);
    k_scanC<<<nb, 256, 0, stream>>>(cnt, part, rowptr, NN);
    k_setE<<<1, 1, 0, stream>>>(rowptr, E);

    hipMemsetAsync(cnt, 0, NN * sizeof(int), stream);  // reuse as cursor
    k_fill<<<(E + 255) / 256, 256, 0, stream>>>(src, dst, E, rowptr, cnt, colidx);

    dim3 g1((NN + 63) / 64, 1);
    // hs1 = dinv .* (x @ W1)
    k_gemm<<<g1, 256, 0, stream>>>(x, W1, dinv, bufA, NN, D1, FIN);
    k_gather64<<<(NN + 3) / 4, 256, 0, stream>>>(rowptr, colidx, dinv, bufA, b1, bufB);

    // hs2 = dinv .* (relu_out @ W2)
    k_gemm<<<g1, 256, 0, stream>>>(bufB, W2, dinv, bufA, NN, C2, D1);
    k_gather47_sm<<<(NN + 3) / 4, 256, 0, stream>>>(rowptr, colidx, dinv, bufA, b2, out);
}

// Round 4
// 228.968 us; speedup vs baseline: 6.4614x; 1.5370x over previous
//
#include <hip/hip_runtime.h>
#include <math.h>

#define NN 100000
#define FIN 256
#define D1 64
#define C2 47
#define S2 48                       // padded layer-2 width (3 x 16)
#define NDB ((NN + 255) / 256)      // 391 blocks for per-node ops
#define PREPB 76                    // (256*64 + 64*48)/256

typedef unsigned short u16;
typedef __attribute__((ext_vector_type(8))) short short8;
typedef __attribute__((ext_vector_type(4))) float floatx4;

__device__ __forceinline__ u16 f2b(float f) {        // fp32 -> bf16 RNE
    union { float f; unsigned u; } v; v.f = f;
    unsigned r = v.u + 0x7FFF + ((v.u >> 16) & 1);
    return (u16)(r >> 16);
}
__device__ __forceinline__ float b2f(u16 h) {
    union { unsigned u; float f; } v; v.u = ((unsigned)h) << 16;
    return v.f;
}

// ---- fused: W1/W2 transpose+convert (blocks 0..75) + degree count w/ ticket ----
__global__ __launch_bounds__(256) void k_prep_count(
    const float* __restrict__ W1, const float* __restrict__ W2,
    u16* __restrict__ W1t, u16* __restrict__ W2t,
    const int* __restrict__ dst, int E,
    int* __restrict__ cnt, int* __restrict__ ticket)
{
    int b = blockIdx.x;
    if (b < PREPB) {
        int i = b * 256 + threadIdx.x;
        if (i < FIN * D1) {                     // W1t[c][k] = bf16(W1[k][c])
            int c = i >> 8, k = i & 255;
            W1t[i] = f2b(W1[k * D1 + c]);
        } else if (i < FIN * D1 + D1 * S2) {    // W2t[c][k], zero-padded col 47
            int j = i - FIN * D1;
            int c = j >> 6, k = j & 63;
            W2t[j] = (c < C2) ? f2b(W2[k * C2 + c]) : (u16)0;
        }
        return;
    }
    int e = (b - PREPB) * 256 + threadIdx.x;
    if (e < E) ticket[e] = atomicAdd(&cnt[dst[e]], 1);
}

// ---- fused: dinv (blocks 0..NDB-1) + scanA block sums ----
__global__ __launch_bounds__(256) void k_dinv_scanA(const int* __restrict__ cnt,
                                                    float* __restrict__ dinv,
                                                    int* __restrict__ part) {
    int b = blockIdx.x, t = threadIdx.x;
    if (b < NDB) {
        int i = b * 256 + t;
        if (i < NN) dinv[i] = rsqrtf((float)cnt[i] + 1.0f);
        return;
    }
    __shared__ int sd[256];
    int base = (b - NDB) * 1024;
    int s = 0;
    #pragma unroll
    for (int j = 0; j < 4; ++j) {
        int idx = base + j * 256 + t;
        if (idx < NN) s += cnt[idx];
    }
    sd[t] = s; __syncthreads();
    for (int off = 128; off; off >>= 1) {
        if (t < off) sd[t] += sd[t + off];
        __syncthreads();
    }
    if (!t) part[b - NDB] = sd[0];
}

__global__ __launch_bounds__(256) void k_scanB(int* __restrict__ part, int nb) {
    __shared__ int sd[256];
    int t = threadIdx.x;
    int v = (t < nb) ? part[t] : 0;
    sd[t] = v; __syncthreads();
    for (int off = 1; off < 256; off <<= 1) {
        int u = (t >= off) ? sd[t - off] : 0;
        __syncthreads();
        sd[t] += u;
        __syncthreads();
    }
    if (t < nb) part[t] = sd[t] - v;  // exclusive
}

__global__ __launch_bounds__(256) void k_scanC(const int* __restrict__ cnt,
                                               const int* __restrict__ part,
                                               int* __restrict__ rowptr, int E) {
    __shared__ int sd[256];
    int t = threadIdx.x, base = blockIdx.x * 1024;
    int i0 = base + t * 4;
    int a0 = 0, a1 = 0, a2 = 0, a3 = 0;
    if (i0 + 0 < NN) a0 = cnt[i0 + 0];
    if (i0 + 1 < NN) a1 = cnt[i0 + 1];
    if (i0 + 2 < NN) a2 = cnt[i0 + 2];
    if (i0 + 3 < NN) a3 = cnt[i0 + 3];
    int ts = a0 + a1 + a2 + a3;
    sd[t] = ts; __syncthreads();
    for (int off = 1; off < 256; off <<= 1) {
        int u = (t >= off) ? sd[t - off] : 0;
        __syncthreads();
        sd[t] += u;
        __syncthreads();
    }
    int run = part[blockIdx.x] + sd[t] - ts;
    if (i0 + 0 < NN) { rowptr[i0 + 0] = run; run += a0; }
    if (i0 + 1 < NN) { rowptr[i0 + 1] = run; run += a1; }
    if (i0 + 2 < NN) { rowptr[i0 + 2] = run; run += a2; }
    if (i0 + 3 < NN) { rowptr[i0 + 3] = run; run += a3; }
    if (blockIdx.x == 0 && t == 0) rowptr[NN] = E;
}

// ---- fused: atomic-free CSR scatter (blocks < nScat) + gemm1 MFMA ----
// gemm1: hs1[r][c] = bf16( dinv[r] * sum_k x[r][k]*W1[k][c] ), 64x64 tile/block.
__global__ __launch_bounds__(256) void k_scatter_gemm1(
    const int* __restrict__ src, const int* __restrict__ dst,
    const int* __restrict__ ticket, const int* __restrict__ rowptr,
    int* __restrict__ colidx, int E, int nScat,
    const float* __restrict__ x, const u16* __restrict__ W1t,
    const float* __restrict__ dinv, u16* __restrict__ hs1)
{
    __shared__ short As[64 * 40];   // [row][k] bf16, stride 40
    __shared__ short Bs[64 * 40];   // [col][k] bf16, stride 40
    int b = blockIdx.x;
    if (b < nScat) {
        int e = b * 256 + threadIdx.x;
        if (e < E) {
            int d = dst[e];
            colidx[rowptr[d] + ticket[e]] = src[e];
        }
        return;
    }
    const int bm = (b - nScat) * 64;
    const int t = threadIdx.x;
    const int w = t >> 6, lane = t & 63;
    const int arow = t >> 2;          // 0..63
    const int ak0 = (t & 3) * 8;      // 0,8,16,24

    floatx4 acc[4] = {};

    for (int kt = 0; kt < FIN; kt += 32) {
        // stage A: fp32 -> bf16
        float4 v0 = make_float4(0.f, 0.f, 0.f, 0.f), v1 = v0;
        int gr = bm + arow;
        if (gr < NN) {
            const float* p = x + (size_t)gr * FIN + kt + ak0;
            v0 = *reinterpret_cast<const float4*>(p);
            v1 = *reinterpret_cast<const float4*>(p + 4);
        }
        short8 av;
        av[0] = (short)f2b(v0.x); av[1] = (short)f2b(v0.y);
        av[2] = (short)f2b(v0.z); av[3] = (short)f2b(v0.w);
        av[4] = (short)f2b(v1.x); av[5] = (short)f2b(v1.y);
        av[6] = (short)f2b(v1.z); av[7] = (short)f2b(v1.w);
        *reinterpret_cast<short8*>(&As[arow * 40 + ak0]) = av;
        // stage B: already bf16, [col][k]
        *reinterpret_cast<short8*>(&Bs[arow * 40 + ak0]) =
            *reinterpret_cast<const short8*>(W1t + arow * FIN + kt + ak0);
        __syncthreads();

        short8 af = *reinterpret_cast<const short8*>(
            &As[(w * 16 + (lane & 15)) * 40 + (lane >> 4) * 8]);
        #pragma unroll
        for (int cb = 0; cb < 4; ++cb) {
            short8 bv = *reinterpret_cast<const short8*>(
                &Bs[(cb * 16 + (lane & 15)) * 40 + (lane >> 4) * 8]);
            acc[cb] = __builtin_amdgcn_mfma_f32_16x16x32_bf16(af, bv, acc[cb], 0, 0, 0);
        }
        __syncthreads();
    }

    #pragma unroll
    for (int cb = 0; cb < 4; ++cb) {
        #pragma unroll
        for (int r = 0; r < 4; ++r) {
            int grow = bm + w * 16 + (lane >> 4) * 4 + r;
            if (grow < NN) {
                float v = acc[cb][r] * dinv[grow];
                hs1[(size_t)grow * D1 + cb * 16 + (lane & 15)] = f2b(v);
            }
        }
    }
}

// ---- gather layer 1 (bf16 in/out): one wave per node, lane = feature ----
__global__ __launch_bounds__(256) void k_gather64(const int* __restrict__ rowptr,
                                                  const int* __restrict__ colidx,
                                                  const float* __restrict__ dinv,
                                                  const u16* __restrict__ hs,
                                                  const float* __restrict__ b1,
                                                  u16* __restrict__ outb) {
    int node = blockIdx.x * 4 + (threadIdx.x >> 6);
    int lane = threadIdx.x & 63;
    if (node >= NN) return;
    int beg = rowptr[node], end = rowptr[node + 1];
    float a0 = b2f(hs[(size_t)node * D1 + lane]);   // self-loop
    float a1 = 0.f, a2 = 0.f, a3 = 0.f;
    int e = beg;
    for (; e + 4 <= end; e += 4) {
        int s0 = colidx[e + 0], s1 = colidx[e + 1];
        int s2 = colidx[e + 2], s3 = colidx[e + 3];
        a0 += b2f(hs[(size_t)s0 * D1 + lane]);
        a1 += b2f(hs[(size_t)s1 * D1 + lane]);
        a2 += b2f(hs[(size_t)s2 * D1 + lane]);
        a3 += b2f(hs[(size_t)s3 * D1 + lane]);
    }
    for (; e < end; ++e) a0 += b2f(hs[(size_t)colidx[e] * D1 + lane]);
    float acc = (a0 + a1) + (a2 + a3);
    outb[(size_t)node * D1 + lane] = f2b(fmaxf(fmaf(dinv[node], acc, b1[lane]), 0.f));
}

// ---- gemm2 MFMA: hs2[r][0..47] = bf16( dinv[r] * h1[r][:] @ W2 ), stride 48 ----
__global__ __launch_bounds__(256) void k_gemm2(const u16* __restrict__ h1,
                                               const u16* __restrict__ W2t,
                                               const float* __restrict__ dinv,
                                               u16* __restrict__ hs2) {
    __shared__ short As[64 * 40];
    __shared__ short Bs[S2 * 40];
    const int bm = blockIdx.x * 64;
    const int t = threadIdx.x;
    const int w = t >> 6, lane = t & 63;
    const int arow = t >> 2;
    const int ak0 = (t & 3) * 8;

    floatx4 acc[3] = {};

    for (int kt = 0; kt < D1; kt += 32) {
        short8 av = {};
        int gr = bm + arow;
        if (gr < NN)
            av = *reinterpret_cast<const short8*>(h1 + (size_t)gr * D1 + kt + ak0);
        *reinterpret_cast<short8*>(&As[arow * 40 + ak0]) = av;
        if (t < S2 * 4) {   // 48 cols x 4 segs
            *reinterpret_cast<short8*>(&Bs[arow * 40 + ak0]) =
                *reinterpret_cast<const short8*>(W2t + arow * D1 + kt + ak0);
        }
        __syncthreads();

        short8 af = *reinterpret_cast<const short8*>(
            &As[(w * 16 + (lane & 15)) * 40 + (lane >> 4) * 8]);
        #pragma unroll
        for (int cb = 0; cb < 3; ++cb) {
            short8 bv = *reinterpret_cast<const short8*>(
                &Bs[(cb * 16 + (lane & 15)) * 40 + (lane >> 4) * 8]);
            acc[cb] = __builtin_amdgcn_mfma_f32_16x16x32_bf16(af, bv, acc[cb], 0, 0, 0);
        }
        __syncthreads();
    }

    #pragma unroll
    for (int cb = 0; cb < 3; ++cb) {
        #pragma unroll
        for (int r = 0; r < 4; ++r) {
            int grow = bm + w * 16 + (lane >> 4) * 4 + r;
            if (grow < NN) {
                float v = acc[cb][r] * dinv[grow];
                hs2[(size_t)grow * S2 + cb * 16 + (lane & 15)] = f2b(v);
            }
        }
    }
}

// ---- gather layer 2 + log_softmax (bf16 in, fp32 out) ----
__global__ __launch_bounds__(256) void k_gather47_sm(const int* __restrict__ rowptr,
                                                     const int* __restrict__ colidx,
                                                     const float* __restrict__ dinv,
                                                     const u16* __restrict__ hs,
                                                     const float* __restrict__ b2,
                                                     float* __restrict__ out) {
    int node = blockIdx.x * 4 + (threadIdx.x >> 6);
    int lane = threadIdx.x & 63;
    if (node >= NN) return;
    int beg = rowptr[node], end = rowptr[node + 1];
    bool act = lane < C2;
    int ll = act ? lane : 0;
    float a0 = b2f(hs[(size_t)node * S2 + ll]);   // self-loop
    float a1 = 0.f, a2 = 0.f, a3 = 0.f;
    int e = beg;
    for (; e + 4 <= end; e += 4) {
        int s0 = colidx[e + 0], s1 = colidx[e + 1];
        int s2 = colidx[e + 2], s3 = colidx[e + 3];
        a0 += b2f(hs[(size_t)s0 * S2 + ll]);
        a1 += b2f(hs[(size_t)s1 * S2 + ll]);
        a2 += b2f(hs[(size_t)s2 * S2 + ll]);
        a3 += b2f(hs[(size_t)s3 * S2 + ll]);
    }
    for (; e < end; ++e) a0 += b2f(hs[(size_t)colidx[e] * S2 + ll]);
    float acc = (a0 + a1) + (a2 + a3);
    float val = fmaf(dinv[node], acc, b2[ll]);

    float m = act ? val : -INFINITY;
    #pragma unroll
    for (int off = 32; off; off >>= 1) m = fmaxf(m, __shfl_xor(m, off));
    float ex = act ? expf(val - m) : 0.f;
    #pragma unroll
    for (int off = 32; off; off >>= 1) ex += __shfl_xor(ex, off);
    if (act) out[(size_t)node * C2 + lane] = val - m - logf(ex);
}

extern "C" void kernel_launch(void* const* d_in, const int* in_sizes, int n_in,
                              void* d_out, int out_size, void* d_ws, size_t ws_size,
                              hipStream_t stream) {
    const float* x  = (const float*)d_in[0];
    const int*   ei = (const int*)d_in[1];
    const float* W1 = (const float*)d_in[2];
    const float* b1 = (const float*)d_in[3];
    const float* W2 = (const float*)d_in[4];
    const float* b2 = (const float*)d_in[5];
    float* out = (float*)d_out;

    const int E = in_sizes[1] / 2;
    const int* src = ei;
    const int* dst = ei + E;

    char* ws = (char*)d_ws;
    float* dinv   = (float*)(ws);                         // 400 KB
    int*   cnt    = (int*)(ws + 0x80000);                 // 400 KB
    int*   rowptr = (int*)(ws + 0x100000);                // 400 KB + 4
    int*   part   = (int*)(ws + 0x180000);                // 392 B
    u16*   W1t    = (u16*)(ws + 0x181000);                // 32 KB
    u16*   W2t    = (u16*)(ws + 0x189000);                // 6 KB
    int*   ticket = (int*)(ws + 0x200000);                // 4.8 MB
    int*   colidx = (int*)(ws + 0x700000);                // 4.8 MB
    u16*   hs1    = (u16*)(ws + 0xC00000);                // 12.8 MB
    u16*   h1r    = (u16*)(ws + 0x1900000);               // 12.8 MB
    u16*   hs2    = (u16*)(ws + 0x2600000);               // 9.6 MB

    const int ebl = (E + 255) / 256;
    const int nb  = (NN + 1023) / 1024;
    const int gb1 = (NN + 63) / 64;

    hipMemsetAsync(cnt, 0, NN * sizeof(int), stream);
    k_prep_count<<<PREPB + ebl, 256, 0, stream>>>(W1, W2, W1t, W2t, dst, E, cnt, ticket);
    k_dinv_scanA<<<NDB + nb, 256, 0, stream>>>(cnt, dinv, part);
    k_scanB<<<1, 256, 0, stream>>>(part, nb);
    k_scanC<<<nb, 256, 0, stream>>>(cnt, part, rowptr, E);

    k_scatter_gemm1<<<ebl + gb1, 256, 0, stream>>>(src, dst, ticket, rowptr, colidx,
                                                   E, ebl, x, W1t, dinv, hs1);
    k_gather64<<<(NN + 3) / 4, 256, 0, stream>>>(rowptr, colidx, dinv, hs1, b1, h1r);
    k_gemm2<<<gb1, 256, 0, stream>>>(h1r, W2t, dinv, hs2);
    k_gather47_sm<<<(NN + 3) / 4, 256, 0, stream>>>(rowptr, colidx, dinv, hs2, b2, out);
}

// Round 5
// 192.234 us; speedup vs baseline: 7.6962x; 1.1911x over previous
//
#include <hip/hip_runtime.h>
#include <math.h>

#define NN 100000
#define FIN 256
#define D1 64
#define C2 47
#define S2 48                       // padded layer-2 width (3 x 16)
#define NDB ((NN + 255) / 256)      // 391 blocks for per-node ops
#define PREPB 76                    // (256*64 + 64*48)/256
#define NB ((NN + 1023) / 1024)     // 98 scan blocks

typedef unsigned short u16;
typedef unsigned int u32;
typedef __attribute__((ext_vector_type(8))) short short8;
typedef __attribute__((ext_vector_type(4))) float floatx4;

__device__ __forceinline__ u16 f2b(float f) {        // fp32 -> bf16 RNE
    union { float f; unsigned u; } v; v.f = f;
    unsigned r = v.u + 0x7FFF + ((v.u >> 16) & 1);
    return (u16)(r >> 16);
}
__device__ __forceinline__ float b2f(u16 h) {
    union { unsigned u; float f; } v; v.u = ((unsigned)h) << 16;
    return v.f;
}
__device__ __forceinline__ float b2f_lo(u32 p) { union { unsigned u; float f; } v; v.u = p << 16; return v.f; }
__device__ __forceinline__ float b2f_hi(u32 p) { union { unsigned u; float f; } v; v.u = p & 0xFFFF0000u; return v.f; }

// ---- fused: W1/W2 transpose+convert (blocks 0..75) + degree count w/ ticket ----
__global__ __launch_bounds__(256) void k_prep_count(
    const float* __restrict__ W1, const float* __restrict__ W2,
    u16* __restrict__ W1t, u16* __restrict__ W2t,
    const int* __restrict__ dst, int E,
    int* __restrict__ cnt, int* __restrict__ ticket)
{
    int b = blockIdx.x;
    if (b < PREPB) {
        int i = b * 256 + threadIdx.x;
        if (i < FIN * D1) {                     // W1t[c][k] = bf16(W1[k][c])
            int c = i >> 8, k = i & 255;
            W1t[i] = f2b(W1[k * D1 + c]);
        } else if (i < FIN * D1 + D1 * S2) {    // W2t[c][k], zero-padded col 47
            int j = i - FIN * D1;
            int c = j >> 6, k = j & 63;
            W2t[j] = (c < C2) ? f2b(W2[k * C2 + c]) : (u16)0;
        }
        return;
    }
    int e = (b - PREPB) * 256 + threadIdx.x;
    if (e < E) ticket[e] = atomicAdd(&cnt[dst[e]], 1);
}

// ---- fused: dinv (blocks 0..NDB-1) + scanA block sums ----
__global__ __launch_bounds__(256) void k_dinv_scanA(const int* __restrict__ cnt,
                                                    float* __restrict__ dinv,
                                                    int* __restrict__ part) {
    int b = blockIdx.x, t = threadIdx.x;
    if (b < NDB) {
        int i = b * 256 + t;
        if (i < NN) dinv[i] = rsqrtf((float)cnt[i] + 1.0f);
        return;
    }
    __shared__ int sd[256];
    int base = (b - NDB) * 1024;
    int s = 0;
    #pragma unroll
    for (int j = 0; j < 4; ++j) {
        int idx = base + j * 256 + t;
        if (idx < NN) s += cnt[idx];
    }
    sd[t] = s; __syncthreads();
    for (int off = 128; off; off >>= 1) {
        if (t < off) sd[t] += sd[t + off];
        __syncthreads();
    }
    if (!t) part[b - NDB] = sd[0];
}

// ---- scanC with inlined block-prefix (scanB folded in) ----
__global__ __launch_bounds__(256) void k_scanC(const int* __restrict__ cnt,
                                               const int* __restrict__ part,
                                               int* __restrict__ rowptr, int E) {
    __shared__ int sd[256];
    int t = threadIdx.x;
    // block prefix = sum part[0 .. blockIdx.x-1]
    int v = (t < (int)blockIdx.x) ? part[t] : 0;
    sd[t] = v; __syncthreads();
    for (int off = 128; off; off >>= 1) {
        if (t < off) sd[t] += sd[t + off];
        __syncthreads();
    }
    int bp = sd[0];
    __syncthreads();

    int base = blockIdx.x * 1024;
    int i0 = base + t * 4;
    int a0 = 0, a1 = 0, a2 = 0, a3 = 0;
    if (i0 + 0 < NN) a0 = cnt[i0 + 0];
    if (i0 + 1 < NN) a1 = cnt[i0 + 1];
    if (i0 + 2 < NN) a2 = cnt[i0 + 2];
    if (i0 + 3 < NN) a3 = cnt[i0 + 3];
    int ts = a0 + a1 + a2 + a3;
    sd[t] = ts; __syncthreads();
    for (int off = 1; off < 256; off <<= 1) {
        int u = (t >= off) ? sd[t - off] : 0;
        __syncthreads();
        sd[t] += u;
        __syncthreads();
    }
    int run = bp + sd[t] - ts;
    if (i0 + 0 < NN) { rowptr[i0 + 0] = run; run += a0; }
    if (i0 + 1 < NN) { rowptr[i0 + 1] = run; run += a1; }
    if (i0 + 2 < NN) { rowptr[i0 + 2] = run; run += a2; }
    if (i0 + 3 < NN) { rowptr[i0 + 3] = run; run += a3; }
    if (blockIdx.x == 0 && t == 0) rowptr[NN] = E;
}

// ---- fused: atomic-free CSR scatter (4 edges/thread ILP) + gemm1 MFMA ----
__global__ __launch_bounds__(256) void k_scatter_gemm1(
    const int* __restrict__ src, const int* __restrict__ dst,
    const int* __restrict__ ticket, const int* __restrict__ rowptr,
    int* __restrict__ colidx, int E, int nScat,
    const float* __restrict__ x, const u16* __restrict__ W1t,
    const float* __restrict__ dinv, u16* __restrict__ hs1)
{
    __shared__ short As[64 * 40];   // [row][k] bf16, stride 40
    __shared__ short Bs[64 * 40];   // [col][k] bf16, stride 40
    int b = blockIdx.x;
    if (b < nScat) {
        int base = b * 1024 + threadIdx.x;
        int d[4], tk[4], sv[4], p[4];
        #pragma unroll
        for (int j = 0; j < 4; ++j) {
            int e = base + j * 256;
            d[j] = -1;
            if (e < E) { d[j] = dst[e]; tk[j] = ticket[e]; sv[j] = src[e]; }
        }
        #pragma unroll
        for (int j = 0; j < 4; ++j) if (d[j] >= 0) p[j] = rowptr[d[j]];
        #pragma unroll
        for (int j = 0; j < 4; ++j) if (d[j] >= 0) colidx[p[j] + tk[j]] = sv[j];
        return;
    }
    const int bm = (b - nScat) * 64;
    const int t = threadIdx.x;
    const int w = t >> 6, lane = t & 63;
    const int arow = t >> 2;          // 0..63
    const int ak0 = (t & 3) * 8;      // 0,8,16,24

    floatx4 acc[4] = {};

    for (int kt = 0; kt < FIN; kt += 32) {
        // stage A: fp32 -> bf16
        float4 v0 = make_float4(0.f, 0.f, 0.f, 0.f), v1 = v0;
        int gr = bm + arow;
        if (gr < NN) {
            const float* p = x + (size_t)gr * FIN + kt + ak0;
            v0 = *reinterpret_cast<const float4*>(p);
            v1 = *reinterpret_cast<const float4*>(p + 4);
        }
        short8 av;
        av[0] = (short)f2b(v0.x); av[1] = (short)f2b(v0.y);
        av[2] = (short)f2b(v0.z); av[3] = (short)f2b(v0.w);
        av[4] = (short)f2b(v1.x); av[5] = (short)f2b(v1.y);
        av[6] = (short)f2b(v1.z); av[7] = (short)f2b(v1.w);
        *reinterpret_cast<short8*>(&As[arow * 40 + ak0]) = av;
        *reinterpret_cast<short8*>(&Bs[arow * 40 + ak0]) =
            *reinterpret_cast<const short8*>(W1t + arow * FIN + kt + ak0);
        __syncthreads();

        short8 af = *reinterpret_cast<const short8*>(
            &As[(w * 16 + (lane & 15)) * 40 + (lane >> 4) * 8]);
        #pragma unroll
        for (int cb = 0; cb < 4; ++cb) {
            short8 bv = *reinterpret_cast<const short8*>(
                &Bs[(cb * 16 + (lane & 15)) * 40 + (lane >> 4) * 8]);
            acc[cb] = __builtin_amdgcn_mfma_f32_16x16x32_bf16(af, bv, acc[cb], 0, 0, 0);
        }
        __syncthreads();
    }

    #pragma unroll
    for (int cb = 0; cb < 4; ++cb) {
        #pragma unroll
        for (int r = 0; r < 4; ++r) {
            int grow = bm + w * 16 + (lane >> 4) * 4 + r;
            if (grow < NN) {
                float v = acc[cb][r] * dinv[grow];
                hs1[(size_t)grow * D1 + cb * 16 + (lane & 15)] = f2b(v);
            }
        }
    }
}

// ---- fused: gather layer 1 (into LDS) + gemm2 MFMA + dinv-scale epilogue ----
// Block owns 64 nodes. Phase 1: each 32-lane group gathers one node row
// (lane covers feats 2l,2l+1 as one u32), ReLU+bias, writes bf16 pair to LDS
// A-tile. Phase 2: gemm2 from LDS, writes hs2 (bf16, stride 48).
__global__ __launch_bounds__(256) void k_gather_gemm2(
    const int* __restrict__ rowptr, const int* __restrict__ colidx,
    const float* __restrict__ dinv, const u16* __restrict__ hs1,
    const float* __restrict__ b1, const u16* __restrict__ W2t,
    u16* __restrict__ hs2)
{
    __shared__ short As[2][64 * 40];   // [kt][row][k%32], stride 40
    __shared__ short Bs[2][48 * 40];
    const int t = threadIdx.x;
    const int bm = blockIdx.x * 64;
    const int w = t >> 6;
    const int l32 = t & 31;

    // stage B (both k-halves) up front
    for (int s = t; s < 384; s += 256) {
        int kt = s / 192, rem = s - kt * 192;
        int r = rem >> 2, j = rem & 3;
        *reinterpret_cast<short8*>(&Bs[kt][r * 40 + j * 8]) =
            *reinterpret_cast<const short8*>(W2t + r * D1 + kt * 32 + j * 8);
    }

    // phase 1: gather 64 node rows into A tile
    {
        const int g = (t >> 5) & 1;                  // half-wave group
        float2 bb = *reinterpret_cast<const float2*>(b1 + 2 * l32);
        const int kth = l32 >> 4;                    // which k-half this lane's feats live in
        const int cs  = (2 * l32) & 31;              // column within half
        #pragma unroll 1
        for (int i = 0; i < 8; ++i) {
            int rl = w * 16 + g * 8 + i;             // 0..63 local row
            int node = bm + rl;
            if (node >= NN) break;
            int beg = rowptr[node], end = rowptr[node + 1];
            const u32* hrow = (const u32*)(hs1 + (size_t)node * D1) + l32;
            u32 pv = *hrow;
            float a0 = b2f_lo(pv), b0 = b2f_hi(pv);
            float a1 = 0.f, b1v = 0.f, a2 = 0.f, b2v = 0.f, a3 = 0.f, b3v = 0.f;
            int e = beg;
            for (; e + 4 <= end; e += 4) {
                int s0 = colidx[e + 0], s1 = colidx[e + 1];
                int s2 = colidx[e + 2], s3 = colidx[e + 3];
                u32 p0 = *((const u32*)(hs1 + (size_t)s0 * D1) + l32);
                u32 p1 = *((const u32*)(hs1 + (size_t)s1 * D1) + l32);
                u32 p2 = *((const u32*)(hs1 + (size_t)s2 * D1) + l32);
                u32 p3 = *((const u32*)(hs1 + (size_t)s3 * D1) + l32);
                a0 += b2f_lo(p0); b0 += b2f_hi(p0);
                a1 += b2f_lo(p1); b1v += b2f_hi(p1);
                a2 += b2f_lo(p2); b2v += b2f_hi(p2);
                a3 += b2f_lo(p3); b3v += b2f_hi(p3);
            }
            for (; e < end; ++e) {
                u32 p0 = *((const u32*)(hs1 + (size_t)colidx[e] * D1) + l32);
                a0 += b2f_lo(p0); b0 += b2f_hi(p0);
            }
            float dd = dinv[node];
            float f0 = fmaxf(fmaf(dd, (a0 + a1) + (a2 + a3), bb.x), 0.f);
            float f1 = fmaxf(fmaf(dd, (b0 + b1v) + (b2v + b3v), bb.y), 0.f);
            u32 pk = (u32)f2b(f0) | ((u32)f2b(f1) << 16);
            *reinterpret_cast<u32*>(&As[kth][rl * 40 + cs]) = pk;
        }
    }
    __syncthreads();

    // phase 2: gemm2
    const int lane = t & 63;
    floatx4 acc[3] = {};
    #pragma unroll
    for (int kt = 0; kt < 2; ++kt) {
        short8 af = *reinterpret_cast<const short8*>(
            &As[kt][(w * 16 + (lane & 15)) * 40 + (lane >> 4) * 8]);
        #pragma unroll
        for (int cb = 0; cb < 3; ++cb) {
            short8 bv = *reinterpret_cast<const short8*>(
                &Bs[kt][(cb * 16 + (lane & 15)) * 40 + (lane >> 4) * 8]);
            acc[cb] = __builtin_amdgcn_mfma_f32_16x16x32_bf16(af, bv, acc[cb], 0, 0, 0);
        }
    }

    #pragma unroll
    for (int cb = 0; cb < 3; ++cb) {
        #pragma unroll
        for (int r = 0; r < 4; ++r) {
            int grow = bm + w * 16 + (lane >> 4) * 4 + r;
            if (grow < NN) {
                float v = acc[cb][r] * dinv[grow];
                hs2[(size_t)grow * S2 + cb * 16 + (lane & 15)] = f2b(v);
            }
        }
    }
}

// ---- gather layer 2 + log_softmax: 2 nodes/wave, 24 active lanes x 2 feats ----
__global__ __launch_bounds__(256) void k_gather47_sm(const int* __restrict__ rowptr,
                                                     const int* __restrict__ colidx,
                                                     const float* __restrict__ dinv,
                                                     const u16* __restrict__ hs,
                                                     const float* __restrict__ b2,
                                                     float* __restrict__ out) {
    int node = blockIdx.x * 8 + (threadIdx.x >> 5);
    int l32 = threadIdx.x & 31;
    if (node >= NN) return;
    bool act = l32 < 24;
    int ll = act ? l32 : 0;
    int f0 = 2 * ll, f1 = f0 + 1;          // f1 == 47 is the zero pad
    int beg = rowptr[node], end = rowptr[node + 1];
    const u32* base = (const u32*)(hs + (size_t)node * S2) + ll;
    u32 pv = *base;
    float a0 = b2f_lo(pv), b0 = b2f_hi(pv);
    float a1 = 0.f, b1v = 0.f, a2 = 0.f, b2v = 0.f, a3 = 0.f, b3v = 0.f;
    int e = beg;
    for (; e + 4 <= end; e += 4) {
        int s0 = colidx[e + 0], s1 = colidx[e + 1];
        int s2 = colidx[e + 2], s3 = colidx[e + 3];
        u32 p0 = *((const u32*)(hs + (size_t)s0 * S2) + ll);
        u32 p1 = *((const u32*)(hs + (size_t)s1 * S2) + ll);
        u32 p2 = *((const u32*)(hs + (size_t)s2 * S2) + ll);
        u32 p3 = *((const u32*)(hs + (size_t)s3 * S2) + ll);
        a0 += b2f_lo(p0); b0 += b2f_hi(p0);
        a1 += b2f_lo(p1); b1v += b2f_hi(p1);
        a2 += b2f_lo(p2); b2v += b2f_hi(p2);
        a3 += b2f_lo(p3); b3v += b2f_hi(p3);
    }
    for (; e < end; ++e) {
        u32 p0 = *((const u32*)(hs + (size_t)colidx[e] * S2) + ll);
        a0 += b2f_lo(p0); b0 += b2f_hi(p0);
    }
    float dd = dinv[node];
    float val0 = fmaf(dd, (a0 + a1) + (a2 + a3), b2[f0]);
    float val1 = (f1 < C2) ? fmaf(dd, (b0 + b1v) + (b2v + b3v), b2[f1]) : -INFINITY;

    float m = act ? fmaxf(val0, val1) : -INFINITY;
    #pragma unroll
    for (int off = 16; off; off >>= 1) m = fmaxf(m, __shfl_xor(m, off));
    float ex = act ? (expf(val0 - m) + ((f1 < C2) ? expf(val1 - m) : 0.f)) : 0.f;
    #pragma unroll
    for (int off = 16; off; off >>= 1) ex += __shfl_xor(ex, off);
    float ls = m + logf(ex);
    if (act) {
        out[(size_t)node * C2 + f0] = val0 - ls;
        if (f1 < C2) out[(size_t)node * C2 + f1] = val1 - ls;
    }
}

extern "C" void kernel_launch(void* const* d_in, const int* in_sizes, int n_in,
                              void* d_out, int out_size, void* d_ws, size_t ws_size,
                              hipStream_t stream) {
    const float* x  = (const float*)d_in[0];
    const int*   ei = (const int*)d_in[1];
    const float* W1 = (const float*)d_in[2];
    const float* b1 = (const float*)d_in[3];
    const float* W2 = (const float*)d_in[4];
    const float* b2 = (const float*)d_in[5];
    float* out = (float*)d_out;

    const int E = in_sizes[1] / 2;
    const int* src = ei;
    const int* dst = ei + E;

    char* ws = (char*)d_ws;
    float* dinv   = (float*)(ws);                         // 400 KB
    int*   cnt    = (int*)(ws + 0x80000);                 // 400 KB
    int*   rowptr = (int*)(ws + 0x100000);                // 400 KB + 4
    int*   part   = (int*)(ws + 0x180000);                // 392 B
    u16*   W1t    = (u16*)(ws + 0x181000);                // 32 KB
    u16*   W2t    = (u16*)(ws + 0x189000);                // 6 KB
    int*   ticket = (int*)(ws + 0x200000);                // 4.8 MB
    int*   colidx = (int*)(ws + 0x700000);                // 4.8 MB
    u16*   hs1    = (u16*)(ws + 0xC00000);                // 12.8 MB
    u16*   hs2    = (u16*)(ws + 0x1900000);               // 9.6 MB

    const int ebl   = (E + 255) / 256;
    const int nScat = (E + 1023) / 1024;
    const int gb1   = (NN + 63) / 64;

    hipMemsetAsync(cnt, 0, NN * sizeof(int), stream);
    k_prep_count<<<PREPB + ebl, 256, 0, stream>>>(W1, W2, W1t, W2t, dst, E, cnt, ticket);
    k_dinv_scanA<<<NDB + NB, 256, 0, stream>>>(cnt, dinv, part);
    k_scanC<<<NB, 256, 0, stream>>>(cnt, part, rowptr, E);

    k_scatter_gemm1<<<nScat + gb1, 256, 0, stream>>>(src, dst, ticket, rowptr, colidx,
                                                     E, nScat, x, W1t, dinv, hs1);
    k_gather_gemm2<<<gb1, 256, 0, stream>>>(rowptr, colidx, dinv, hs1, b1, W2t, hs2);
    k_gather47_sm<<<(NN + 7) / 8, 256, 0, stream>>>(rowptr, colidx, dinv, hs2, b2, out);
}

// Round 6
// 143.105 us; speedup vs baseline: 10.3383x; 1.3433x over previous
//
#include <hip/hip_runtime.h>
#include <math.h>

#define NN 100000
#define FIN 256
#define D1 64
#define C2 47
#define S2 48                       // padded layer-2 width (3 x 16)
#define PREPB 76                    // (256*64 + 64*48)/256
#define NBKT 391                    // ceil(NN/256) buckets of 256 nodes
#define CAP 4096                    // intermediate capacity per bucket (avg 3070)

typedef unsigned short u16;
typedef unsigned int u32;
typedef __attribute__((ext_vector_type(8))) short short8;
typedef __attribute__((ext_vector_type(4))) float floatx4;

__device__ __forceinline__ u16 f2b(float f) {        // fp32 -> bf16 RNE
    union { float f; unsigned u; } v; v.f = f;
    unsigned r = v.u + 0x7FFF + ((v.u >> 16) & 1);
    return (u16)(r >> 16);
}
__device__ __forceinline__ float b2f_lo(u32 p) { union { unsigned u; float f; } v; v.u = p << 16; return v.f; }
__device__ __forceinline__ float b2f_hi(u32 p) { union { unsigned u; float f; } v; v.u = p & 0xFFFF0000u; return v.f; }

// ---- launch 1: W1/W2 transpose+convert (blocks 0..75) + edge bucketing ----
// bucket = dst >> 8 (391 buckets x 256 nodes). Packed edge: src | dstLocal<<17.
__global__ __launch_bounds__(256) void k_prep_bucket(
    const float* __restrict__ W1, const float* __restrict__ W2,
    u16* __restrict__ W1t, u16* __restrict__ W2t,
    const int* __restrict__ src, const int* __restrict__ dst, int E,
    int* __restrict__ bucketCnt, u32* __restrict__ ebuf)
{
    int b = blockIdx.x;
    if (b < PREPB) {
        int i = b * 256 + threadIdx.x;
        if (i < FIN * D1) {                     // W1t[c][k] = bf16(W1[k][c])
            int c = i >> 8, k = i & 255;
            W1t[i] = f2b(W1[k * D1 + c]);
        } else if (i < FIN * D1 + D1 * S2) {    // W2t[c][k], zero-padded col 47
            int j = i - FIN * D1;
            int c = j >> 6, k = j & 63;
            W2t[j] = (c < C2) ? f2b(W2[k * C2 + c]) : (u16)0;
        }
        return;
    }
    __shared__ int hist[NBKT];
    __shared__ int base[NBKT];
    const int t = threadIdx.x;
    const int blk = b - PREPB;
    for (int i = t; i < NBKT; i += 256) hist[i] = 0;
    __syncthreads();

    int e0 = blk * 2048 + t;
    u32 pk[8]; int bk[8], tk[8];
    #pragma unroll
    for (int j = 0; j < 8; ++j) {
        int e = e0 + j * 256;
        bk[j] = -1;
        if (e < E) {
            int d = dst[e];
            int s = src[e];
            bk[j] = d >> 8;
            pk[j] = (u32)s | ((u32)(d & 255) << 17);
            tk[j] = atomicAdd(&hist[bk[j]], 1);
        }
    }
    __syncthreads();
    for (int i = t; i < NBKT; i += 256)
        base[i] = hist[i] ? atomicAdd(&bucketCnt[i], hist[i]) : 0;
    __syncthreads();
    #pragma unroll
    for (int j = 0; j < 8; ++j)
        if (bk[j] >= 0)
            ebuf[(size_t)bk[j] * CAP + base[bk[j]] + tk[j]] = pk[j];
}

// ---- launch 2: per-bucket node histogram + scan -> rowptr, dinv ----
__global__ __launch_bounds__(256) void k_csr_ptr(const int* __restrict__ bucketCnt,
                                                 const u32* __restrict__ ebuf,
                                                 int* __restrict__ rowptr,
                                                 float* __restrict__ dinv, int E) {
    __shared__ int sd[256];
    __shared__ int hist[256];
    const int b = blockIdx.x, t = threadIdx.x;
    // ebase = sum bucketCnt[0..b-1]  (NBKT=391 <= 512)
    int v = ((t < b) ? bucketCnt[t] : 0) + ((t + 256 < b) ? bucketCnt[t + 256] : 0);
    sd[t] = v; __syncthreads();
    for (int off = 128; off; off >>= 1) {
        if (t < off) sd[t] += sd[t + off];
        __syncthreads();
    }
    int ebase = sd[0];
    __syncthreads();

    hist[t] = 0;
    __syncthreads();
    const int cnt = bucketCnt[b];
    const u32* eb = ebuf + (size_t)b * CAP;
    for (int i = t; i < cnt; i += 256)
        atomicAdd(&hist[eb[i] >> 17], 1);
    __syncthreads();

    int h = hist[t];
    sd[t] = h; __syncthreads();
    for (int off = 1; off < 256; off <<= 1) {
        int u = (t >= off) ? sd[t - off] : 0;
        __syncthreads();
        sd[t] += u;
        __syncthreads();
    }
    int node = b * 256 + t;
    if (node <= NN) rowptr[node] = ebase + sd[t] - h;
    if (node < NN) dinv[node] = rsqrtf((float)h + 1.0f);
}

// ---- launch 3: bucket-local CSR fill (blocks < NBKT) + gemm1 MFMA ----
// gemm1: hs1[r][c] = bf16( dinv[r] * sum_k x[r][k]*W1[k][c] ), ping-pong LDS.
__global__ __launch_bounds__(256) void k_fill_gemm1(
    const int* __restrict__ bucketCnt, const u32* __restrict__ ebuf,
    const int* __restrict__ rowptr, int* __restrict__ colidx,
    const float* __restrict__ x, const u16* __restrict__ W1t,
    const float* __restrict__ dinv, u16* __restrict__ hs1)
{
    int b = blockIdx.x;
    const int t = threadIdx.x;
    if (b < NBKT) {
        __shared__ int cur[256];
        int node = b * 256 + t;
        cur[t] = (node < NN) ? rowptr[node] : 0;
        __syncthreads();
        const int cnt = bucketCnt[b];
        const u32* eb = ebuf + (size_t)b * CAP;
        for (int i = t; i < cnt; i += 256) {
            u32 p = eb[i];
            int pos = atomicAdd(&cur[p >> 17], 1);
            colidx[pos] = p & 0x1FFFF;
        }
        return;
    }
    __shared__ short As[2][64 * 40];   // [buf][row][k], stride 40
    __shared__ short Bs[2][64 * 40];   // [buf][col][k]
    const int bm = (b - NBKT) * 64;
    const int w = t >> 6, lane = t & 63;
    const int arow = t >> 2;          // 0..63
    const int ak0 = (t & 3) * 8;      // 0,8,16,24

    floatx4 acc[4] = {};
    const int gr = bm + arow;
    const bool rowok = gr < NN;
    const float* xrow = x + (size_t)(rowok ? gr : 0) * FIN + ak0;

    // prologue: stage tile 0
    float4 v0 = make_float4(0.f,0.f,0.f,0.f), v1 = v0;
    if (rowok) { v0 = *(const float4*)(xrow); v1 = *(const float4*)(xrow + 4); }
    short8 wv = *(const short8*)(W1t + arow * FIN + ak0);
    {
        short8 av;
        av[0]=(short)f2b(v0.x); av[1]=(short)f2b(v0.y); av[2]=(short)f2b(v0.z); av[3]=(short)f2b(v0.w);
        av[4]=(short)f2b(v1.x); av[5]=(short)f2b(v1.y); av[6]=(short)f2b(v1.z); av[7]=(short)f2b(v1.w);
        *(short8*)(&As[0][arow * 40 + ak0]) = av;
        *(short8*)(&Bs[0][arow * 40 + ak0]) = wv;
    }
    __syncthreads();

    int cb_ = 0;
    for (int kt = 32; kt <= FIN; kt += 32) {
        const bool more = kt < FIN;
        float4 n0, n1; short8 nw;
        if (more) {                       // issue next-tile loads early
            if (rowok) { n0 = *(const float4*)(xrow + kt); n1 = *(const float4*)(xrow + kt + 4); }
            else { n0 = make_float4(0.f,0.f,0.f,0.f); n1 = n0; }
            nw = *(const short8*)(W1t + arow * FIN + kt + ak0);
        }
        short8 af = *(const short8*)(&As[cb_][(w * 16 + (lane & 15)) * 40 + (lane >> 4) * 8]);
        #pragma unroll
        for (int cb = 0; cb < 4; ++cb) {
            short8 bv = *(const short8*)(&Bs[cb_][(cb * 16 + (lane & 15)) * 40 + (lane >> 4) * 8]);
            acc[cb] = __builtin_amdgcn_mfma_f32_16x16x32_bf16(af, bv, acc[cb], 0, 0, 0);
        }
        if (!more) break;
        short8 av;
        av[0]=(short)f2b(n0.x); av[1]=(short)f2b(n0.y); av[2]=(short)f2b(n0.z); av[3]=(short)f2b(n0.w);
        av[4]=(short)f2b(n1.x); av[5]=(short)f2b(n1.y); av[6]=(short)f2b(n1.z); av[7]=(short)f2b(n1.w);
        *(short8*)(&As[cb_ ^ 1][arow * 40 + ak0]) = av;
        *(short8*)(&Bs[cb_ ^ 1][arow * 40 + ak0]) = nw;
        __syncthreads();
        cb_ ^= 1;
    }

    #pragma unroll
    for (int cb = 0; cb < 4; ++cb) {
        #pragma unroll
        for (int r = 0; r < 4; ++r) {
            int grow = bm + w * 16 + (lane >> 4) * 4 + r;
            if (grow < NN) {
                float v = acc[cb][r] * dinv[grow];
                hs1[(size_t)grow * D1 + cb * 16 + (lane & 15)] = f2b(v);
            }
        }
    }
}

// ---- launch 4: gather layer 1 (into LDS) + gemm2 MFMA + dinv-scale epilogue --
__global__ __launch_bounds__(256) void k_gather_gemm2(
    const int* __restrict__ rowptr, const int* __restrict__ colidx,
    const float* __restrict__ dinv, const u16* __restrict__ hs1,
    const float* __restrict__ b1, const u16* __restrict__ W2t,
    u16* __restrict__ hs2)
{
    __shared__ short As[2][64 * 40];   // [kt][row][k%32], stride 40
    __shared__ short Bs[2][48 * 40];
    const int t = threadIdx.x;
    const int bm = blockIdx.x * 64;
    const int w = t >> 6;
    const int l32 = t & 31;

    for (int s = t; s < 384; s += 256) {
        int kt = s / 192, rem = s - kt * 192;
        int r = rem >> 2, j = rem & 3;
        *(short8*)(&Bs[kt][r * 40 + j * 8]) =
            *(const short8*)(W2t + r * D1 + kt * 32 + j * 8);
    }

    {
        const int g = (t >> 5) & 1;
        float2 bb = *(const float2*)(b1 + 2 * l32);
        const int kth = l32 >> 4;
        const int cs  = (2 * l32) & 31;
        #pragma unroll 1
        for (int i = 0; i < 8; ++i) {
            int rl = w * 16 + g * 8 + i;
            int node = bm + rl;
            if (node >= NN) break;
            int beg = rowptr[node], end = rowptr[node + 1];
            u32 pv = *((const u32*)(hs1 + (size_t)node * D1) + l32);
            float a0 = b2f_lo(pv), b0 = b2f_hi(pv);
            float a1 = 0.f, b1v = 0.f, a2 = 0.f, b2v = 0.f, a3 = 0.f, b3v = 0.f;
            int e = beg;
            for (; e + 8 <= end; e += 8) {
                int s0 = colidx[e+0], s1 = colidx[e+1], s2 = colidx[e+2], s3 = colidx[e+3];
                int s4 = colidx[e+4], s5 = colidx[e+5], s6 = colidx[e+6], s7 = colidx[e+7];
                u32 p0 = *((const u32*)(hs1 + (size_t)s0 * D1) + l32);
                u32 p1 = *((const u32*)(hs1 + (size_t)s1 * D1) + l32);
                u32 p2 = *((const u32*)(hs1 + (size_t)s2 * D1) + l32);
                u32 p3 = *((const u32*)(hs1 + (size_t)s3 * D1) + l32);
                u32 p4 = *((const u32*)(hs1 + (size_t)s4 * D1) + l32);
                u32 p5 = *((const u32*)(hs1 + (size_t)s5 * D1) + l32);
                u32 p6 = *((const u32*)(hs1 + (size_t)s6 * D1) + l32);
                u32 p7 = *((const u32*)(hs1 + (size_t)s7 * D1) + l32);
                a0 += b2f_lo(p0); b0  += b2f_hi(p0);
                a1 += b2f_lo(p1); b1v += b2f_hi(p1);
                a2 += b2f_lo(p2); b2v += b2f_hi(p2);
                a3 += b2f_lo(p3); b3v += b2f_hi(p3);
                a0 += b2f_lo(p4); b0  += b2f_hi(p4);
                a1 += b2f_lo(p5); b1v += b2f_hi(p5);
                a2 += b2f_lo(p6); b2v += b2f_hi(p6);
                a3 += b2f_lo(p7); b3v += b2f_hi(p7);
            }
            for (; e + 4 <= end; e += 4) {
                int s0 = colidx[e+0], s1 = colidx[e+1], s2 = colidx[e+2], s3 = colidx[e+3];
                u32 p0 = *((const u32*)(hs1 + (size_t)s0 * D1) + l32);
                u32 p1 = *((const u32*)(hs1 + (size_t)s1 * D1) + l32);
                u32 p2 = *((const u32*)(hs1 + (size_t)s2 * D1) + l32);
                u32 p3 = *((const u32*)(hs1 + (size_t)s3 * D1) + l32);
                a0 += b2f_lo(p0); b0  += b2f_hi(p0);
                a1 += b2f_lo(p1); b1v += b2f_hi(p1);
                a2 += b2f_lo(p2); b2v += b2f_hi(p2);
                a3 += b2f_lo(p3); b3v += b2f_hi(p3);
            }
            for (; e < end; ++e) {
                u32 p0 = *((const u32*)(hs1 + (size_t)colidx[e] * D1) + l32);
                a0 += b2f_lo(p0); b0 += b2f_hi(p0);
            }
            float dd = dinv[node];
            float f0 = fmaxf(fmaf(dd, (a0 + a1) + (a2 + a3), bb.x), 0.f);
            float f1 = fmaxf(fmaf(dd, (b0 + b1v) + (b2v + b3v), bb.y), 0.f);
            u32 pk = (u32)f2b(f0) | ((u32)f2b(f1) << 16);
            *(u32*)(&As[kth][rl * 40 + cs]) = pk;
        }
    }
    __syncthreads();

    const int lane = t & 63;
    floatx4 acc[3] = {};
    #pragma unroll
    for (int kt = 0; kt < 2; ++kt) {
        short8 af = *(const short8*)(&As[kt][(w * 16 + (lane & 15)) * 40 + (lane >> 4) * 8]);
        #pragma unroll
        for (int cb = 0; cb < 3; ++cb) {
            short8 bv = *(const short8*)(&Bs[kt][(cb * 16 + (lane & 15)) * 40 + (lane >> 4) * 8]);
            acc[cb] = __builtin_amdgcn_mfma_f32_16x16x32_bf16(af, bv, acc[cb], 0, 0, 0);
        }
    }

    #pragma unroll
    for (int cb = 0; cb < 3; ++cb) {
        #pragma unroll
        for (int r = 0; r < 4; ++r) {
            int grow = bm + w * 16 + (lane >> 4) * 4 + r;
            if (grow < NN) {
                float v = acc[cb][r] * dinv[grow];
                hs2[(size_t)grow * S2 + cb * 16 + (lane & 15)] = f2b(v);
            }
        }
    }
}

// ---- launch 5: gather layer 2 + log_softmax: 2 nodes/wave ----
__global__ __launch_bounds__(256) void k_gather47_sm(const int* __restrict__ rowptr,
                                                     const int* __restrict__ colidx,
                                                     const float* __restrict__ dinv,
                                                     const u16* __restrict__ hs,
                                                     const float* __restrict__ b2,
                                                     float* __restrict__ out) {
    int node = blockIdx.x * 8 + (threadIdx.x >> 5);
    int l32 = threadIdx.x & 31;
    if (node >= NN) return;
    bool act = l32 < 24;
    int ll = act ? l32 : 0;
    int f0 = 2 * ll, f1 = f0 + 1;
    int beg = rowptr[node], end = rowptr[node + 1];
    u32 pv = *((const u32*)(hs + (size_t)node * S2) + ll);
    float a0 = b2f_lo(pv), b0 = b2f_hi(pv);
    float a1 = 0.f, b1v = 0.f, a2 = 0.f, b2v = 0.f, a3 = 0.f, b3v = 0.f;
    int e = beg;
    for (; e + 8 <= end; e += 8) {
        int s0 = colidx[e+0], s1 = colidx[e+1], s2 = colidx[e+2], s3 = colidx[e+3];
        int s4 = colidx[e+4], s5 = colidx[e+5], s6 = colidx[e+6], s7 = colidx[e+7];
        u32 p0 = *((const u32*)(hs + (size_t)s0 * S2) + ll);
        u32 p1 = *((const u32*)(hs + (size_t)s1 * S2) + ll);
        u32 p2 = *((const u32*)(hs + (size_t)s2 * S2) + ll);
        u32 p3 = *((const u32*)(hs + (size_t)s3 * S2) + ll);
        u32 p4 = *((const u32*)(hs + (size_t)s4 * S2) + ll);
        u32 p5 = *((const u32*)(hs + (size_t)s5 * S2) + ll);
        u32 p6 = *((const u32*)(hs + (size_t)s6 * S2) + ll);
        u32 p7 = *((const u32*)(hs + (size_t)s7 * S2) + ll);
        a0 += b2f_lo(p0); b0  += b2f_hi(p0);
        a1 += b2f_lo(p1); b1v += b2f_hi(p1);
        a2 += b2f_lo(p2); b2v += b2f_hi(p2);
        a3 += b2f_lo(p3); b3v += b2f_hi(p3);
        a0 += b2f_lo(p4); b0  += b2f_hi(p4);
        a1 += b2f_lo(p5); b1v += b2f_hi(p5);
        a2 += b2f_lo(p6); b2v += b2f_hi(p6);
        a3 += b2f_lo(p7); b3v += b2f_hi(p7);
    }
    for (; e + 4 <= end; e += 4) {
        int s0 = colidx[e+0], s1 = colidx[e+1], s2 = colidx[e+2], s3 = colidx[e+3];
        u32 p0 = *((const u32*)(hs + (size_t)s0 * S2) + ll);
        u32 p1 = *((const u32*)(hs + (size_t)s1 * S2) + ll);
        u32 p2 = *((const u32*)(hs + (size_t)s2 * S2) + ll);
        u32 p3 = *((const u32*)(hs + (size_t)s3 * S2) + ll);
        a0 += b2f_lo(p0); b0  += b2f_hi(p0);
        a1 += b2f_lo(p1); b1v += b2f_hi(p1);
        a2 += b2f_lo(p2); b2v += b2f_hi(p2);
        a3 += b2f_lo(p3); b3v += b2f_hi(p3);
    }
    for (; e < end; ++e) {
        u32 p0 = *((const u32*)(hs + (size_t)colidx[e] * S2) + ll);
        a0 += b2f_lo(p0); b0 += b2f_hi(p0);
    }
    float dd = dinv[node];
    float val0 = fmaf(dd, (a0 + a1) + (a2 + a3), b2[f0]);
    float val1 = (f1 < C2) ? fmaf(dd, (b0 + b1v) + (b2v + b3v), b2[f1]) : -INFINITY;

    float m = act ? fmaxf(val0, val1) : -INFINITY;
    #pragma unroll
    for (int off = 16; off; off >>= 1) m = fmaxf(m, __shfl_xor(m, off));
    float ex = act ? (expf(val0 - m) + ((f1 < C2) ? expf(val1 - m) : 0.f)) : 0.f;
    #pragma unroll
    for (int off = 16; off; off >>= 1) ex += __shfl_xor(ex, off);
    float ls = m + logf(ex);
    if (act) {
        out[(size_t)node * C2 + f0] = val0 - ls;
        if (f1 < C2) out[(size_t)node * C2 + f1] = val1 - ls;
    }
}

extern "C" void kernel_launch(void* const* d_in, const int* in_sizes, int n_in,
                              void* d_out, int out_size, void* d_ws, size_t ws_size,
                              hipStream_t stream) {
    const float* x  = (const float*)d_in[0];
    const int*   ei = (const int*)d_in[1];
    const float* W1 = (const float*)d_in[2];
    const float* b1 = (const float*)d_in[3];
    const float* W2 = (const float*)d_in[4];
    const float* b2 = (const float*)d_in[5];
    float* out = (float*)d_out;

    const int E = in_sizes[1] / 2;
    const int* src = ei;
    const int* dst = ei + E;

    char* ws = (char*)d_ws;
    float* dinv      = (float*)(ws);               // 400 KB
    int*   bucketCnt = (int*)(ws + 0x80000);       // 1.6 KB
    int*   rowptr    = (int*)(ws + 0x100000);      // 400 KB + 4
    u16*   W1t       = (u16*)(ws + 0x180000);      // 32 KB
    u16*   W2t       = (u16*)(ws + 0x189000);      // 6 KB
    u32*   ebuf      = (u32*)(ws + 0x200000);      // 6.4 MB (391*4096*4)
    int*   colidx    = (int*)(ws + 0x900000);      // 4.8 MB
    u16*   hs1       = (u16*)(ws + 0xE00000);      // 12.8 MB
    u16*   hs2       = (u16*)(ws + 0x1B00000);     // 9.6 MB

    const int nBk1 = (E + 2047) / 2048;            // pass-1 bucket blocks
    const int gb1  = (NN + 63) / 64;               // 1563 gemm blocks

    hipMemsetAsync(bucketCnt, 0, NBKT * sizeof(int), stream);
    k_prep_bucket<<<PREPB + nBk1, 256, 0, stream>>>(W1, W2, W1t, W2t, src, dst, E,
                                                    bucketCnt, ebuf);
    k_csr_ptr<<<NBKT, 256, 0, stream>>>(bucketCnt, ebuf, rowptr, dinv, E);
    k_fill_gemm1<<<NBKT + gb1, 256, 0, stream>>>(bucketCnt, ebuf, rowptr, colidx,
                                                 x, W1t, dinv, hs1);
    k_gather_gemm2<<<gb1, 256, 0, stream>>>(rowptr, colidx, dinv, hs1, b1, W2t, hs2);
    k_gather47_sm<<<(NN + 7) / 8, 256, 0, stream>>>(rowptr, colidx, dinv, hs2, b2, out);
}